// Round 8
// baseline (937.340 us; speedup 1.0000x reference)
//
#include <hip/hip_runtime.h>
#include <stdint.h>

// Problem constants (B, LQ, LK, D fixed by the reference)
#define NB    32
#define SLQ   2048
#define SLK   2048
#define DD    128
#define QTILE 128          // q rows per workgroup (4 waves x 32)
#define KVB   64           // keys per block iteration

typedef __attribute__((ext_vector_type(8)))  short    bf16x8;
typedef __attribute__((ext_vector_type(16))) float    f32x16;
typedef __attribute__((ext_vector_type(4)))  float    f32x4v;
typedef __attribute__((ext_vector_type(4)))  uint32_t u32x4;
typedef __attribute__((ext_vector_type(2)))  uint32_t u32x2;

union FragU { uint32_t u[4]; bf16x8 v; };

// HW packed f32->bf16 (RNE), 1 inst per pair
__device__ __forceinline__ uint32_t cvtpk(float lo, float hi) {
    uint32_t r;
    asm("v_cvt_pk_bf16_f32 %0, %1, %2" : "=v"(r) : "v"(lo), "v"(hi));
    return r;
}
// a' = {lanes<32: a, lanes>=32: b[lane-32]}; b' = {lanes<32: a[lane+32], lanes>=32: b}
__device__ __forceinline__ void perm32swap(uint32_t& a, uint32_t& b) {
    asm("v_permlane32_swap_b32 %0, %1" : "+v"(a), "+v"(b));
}
// 16 mask bytes (0/1) -> 16 bits
__device__ __forceinline__ uint32_t pack16(u32x4 a) {
    uint32_t r0 = (((a.x & 0x01010101u) * 0x01020408u) >> 24) & 0xFu;
    uint32_t r1 = (((a.y & 0x01010101u) * 0x01020408u) >> 24) & 0xFu;
    uint32_t r2 = (((a.z & 0x01010101u) * 0x01020408u) >> 24) & 0xFu;
    uint32_t r3 = (((a.w & 0x01010101u) * 0x01020408u) >> 24) & 0xFu;
    return r0 | (r1 << 4) | (r2 << 8) | (r3 << 12);
}
#if __has_builtin(__builtin_amdgcn_exp2f)
#define EXP2(x) __builtin_amdgcn_exp2f(x)
#else
#define EXP2(x) exp2f(x)
#endif

// NSPLIT=2: each block covers SLK/2 keys; writes un-normalized num to ws and
// den (row exp-sums) to ws; a combine kernel finishes. Exact because the
// reference softmax is unnormalized exp (linear in key-partitions).
// NSPLIT=1: R5-identical single-pass (fallback when ws is too small).
template <int NSPLIT>
__global__ __launch_bounds__(256, 4)
void attn_fwd(const float* __restrict__ qp, const float* __restrict__ kp,
              const float* __restrict__ vp, const void* __restrict__ mp,
              float* __restrict__ op, float* __restrict__ wsp)
{
    constexpr int NKBE = SLK / NSPLIT / KVB;  // key-block iterations per block
    // Single-buffer LDS (R5-proven schedule): 16KB K + 16KB V^T + 1KB mask bits
    __shared__ short    k_lds[KVB * DD];    // [64 key][128 d] bf16, 16B-XOR swizzle
    __shared__ short    vt_lds[DD * KVB];   // [128 d][64 key] bf16, 8B-XOR swizzle
    __shared__ uint32_t m_lds[QTILE * 2];   // [128 q][2] dwords of key-bits
    __shared__ int      det_flags;

    const int tid  = threadIdx.x;
    const int lane = tid & 63;
    const int wv   = tid >> 6;   // wave 0..3
    const int l31  = lane & 31;
    const int hi2  = lane >> 5;  // 0/1

    // XCD-chunked swizzle over the full grid
    const int nwg   = 512 * NSPLIT;
    const int chunk = nwg / 8;
    const int bid = blockIdx.x;
    const int wg  = (bid % 8) * chunk + (bid / 8);
    const int qt  = wg / NSPLIT;              // q-tile id 0..511
    const int ks  = wg % NSPLIT;              // key split id
    const int b   = qt >> 4;                  // batch
    const int q0  = (qt & 15) * QTILE;        // q tile origin
    const int koff = ks * (SLK / NSPLIT);     // key range origin

    // ---- mask dtype self-detection (R2 FETCH proved u8; keep as safety) ----
    if (tid == 0) det_flags = 0;
    __syncthreads();
    {
        const u32x4 w = *(const u32x4*)((const char*)mp + tid * 16);
        const uint32_t any_hi    = (w.x | w.y | w.z | w.w) & 0xFFFFFF00u;
        const uint32_t any_mod84 = (w.y | w.w) & 0xFFu;
        const int f = (any_hi ? 1 : 0) | (any_mod84 ? 2 : 0);
        if (f) atomicOr(&det_flags, f);
    }
    __syncthreads();
    const int mflags = det_flags;
    const int mmode  = (mflags & 1) ? 0 : ((mflags & 2) ? 1 : 2);  // 0=u8, 1=i32, 2=i64

    // scale = log2(e)/sqrt(128): scores land in log2 units -> softmax is bare v_exp
    const float qsc = 0.12751744846458246f;

    // ---- persistent Q fragments (B-operand of swapped QK^T) ----
    bf16x8 qf[8];
    {
        const float* qrow = qp + ((size_t)b * SLQ + (size_t)(q0 + wv * 32 + l31)) * DD;
        #pragma unroll
        for (int kss = 0; kss < 8; ++kss) {
            f32x4v x0 = *(const f32x4v*)(qrow + 16 * kss + 8 * hi2);
            f32x4v x1 = *(const f32x4v*)(qrow + 16 * kss + 8 * hi2 + 4);
            FragU f;
            f.u[0] = cvtpk(x0.x * qsc, x0.y * qsc);
            f.u[1] = cvtpk(x0.z * qsc, x0.w * qsc);
            f.u[2] = cvtpk(x1.x * qsc, x1.y * qsc);
            f.u[3] = cvtpk(x1.z * qsc, x1.w * qsc);
            qf[kss] = f.v;
        }
    }

    f32x16 oacc[4];
    #pragma unroll
    for (int i = 0; i < 4; ++i)
        #pragma unroll
        for (int j = 0; j < 16; ++j) oacc[i][j] = 0.0f;
    float psum = 0.0f;

    const float* kb0 = kp + (size_t)b * SLK * DD;
    const float* vb0 = vp + (size_t)b * SLK * DD;
    const size_t mrow0 = ((size_t)b * SLQ + q0) * SLK;

    // ---- prefetch registers (T14: issue-early / write-late) ----
    f32x4v kreg[8];
    float  vreg[32];
    u32x4  mreg[2];

    const int vd  = tid & 127;       // d-row this thread stages for V^T
    const int vkh = tid >> 7;        // key half (0: keys 0-31, 1: keys 32-63)
    const int mqq = tid >> 1;        // mask q row
    const int mh  = tid & 1;         // mask key half
    const int swv = (vd & 15) << 3;  // V^T 8B-granular XOR

    #define LOAD_TILE(KB)                                                         \
        do {                                                                      \
            const int k0_ = koff + (KB) * KVB;                                    \
            const float* kbase_ = kb0 + (size_t)k0_ * DD;                         \
            _Pragma("unroll")                                                     \
            for (int j = 0; j < 8; ++j)                                           \
                kreg[j] = *(const f32x4v*)(kbase_ + (j * 256 + tid) * 4);         \
            const float* vcol_ = vb0 + ((size_t)k0_ + 32 * vkh) * DD + vd;        \
            _Pragma("unroll")                                                     \
            for (int jj = 0; jj < 32; ++jj) vreg[jj] = vcol_[(size_t)jj * DD];    \
            if (mmode == 0) {                                                     \
                const uint8_t* ms_ = (const uint8_t*)mp + mrow0 +                 \
                                     (size_t)mqq * SLK + k0_ + mh * 32;           \
                mreg[0] = *(const u32x4*)(ms_);                                   \
                mreg[1] = *(const u32x4*)(ms_ + 16);                              \
            }                                                                     \
        } while (0)

    #define WRITE_LDS(KB)                                                         \
        do {                                                                      \
            _Pragma("unroll")                                                     \
            for (int j = 0; j < 8; ++j) {                                         \
                const int flat = (j * 256 + tid) * 4;                             \
                const int kk   = flat >> 7;                                       \
                const int dd2  = (flat & 127) * 2;                                \
                u32x2 w2;                                                         \
                w2.x = cvtpk(kreg[j].x, kreg[j].y);                               \
                w2.y = cvtpk(kreg[j].z, kreg[j].w);                               \
                *(u32x2*)((char*)k_lds + kk * 256 + (dd2 ^ ((kk & 7) << 4))) = w2;\
            }                                                                     \
            {                                                                     \
                char* vrow_ = (char*)vt_lds + vd * 128;                           \
                _Pragma("unroll")                                                 \
                for (int j = 0; j < 8; ++j) {                                     \
                    u32x2 w2;                                                     \
                    w2.x = cvtpk(vreg[4 * j + 0], vreg[4 * j + 1]);               \
                    w2.y = cvtpk(vreg[4 * j + 2], vreg[4 * j + 3]);               \
                    *(u32x2*)(vrow_ + ((vkh * 64 + 8 * j) ^ swv)) = w2;           \
                }                                                                 \
            }                                                                     \
            if (mmode == 0) {                                                     \
                m_lds[mqq * 2 + mh] = pack16(mreg[0]) | (pack16(mreg[1]) << 16);  \
            } else {                                                              \
                const size_t e0_ = mrow0 + (size_t)mqq * SLK + koff + (KB) * KVB + mh * 32; \
                uint32_t bits = 0;                                                \
                if (mmode == 1) {                                                 \
                    const uint32_t* s_ = (const uint32_t*)mp + e0_;               \
                    for (int j = 0; j < 32; ++j) bits |= (s_[j] ? 1u : 0u) << j;  \
                } else {                                                          \
                    const uint64_t* s_ = (const uint64_t*)mp + e0_;               \
                    for (int j = 0; j < 32; ++j) bits |= (s_[j] ? 1u : 0u) << j;  \
                }                                                                 \
                m_lds[mqq * 2 + mh] = bits;                                       \
            }                                                                     \
        } while (0)

    LOAD_TILE(0);

    for (int kb = 0; kb < NKBE; ++kb) {
        // ---- write LDS from prefetch regs; vmcnt wait lands HERE, pinned by
        //      the barrier structure (a full compute phase has hidden the loads)
        WRITE_LDS(kb);
        __syncthreads();

        // ---- issue next tile's loads, pinned above compute ----
        if (kb + 1 < NKBE) LOAD_TILE(kb + 1);
        __builtin_amdgcn_sched_barrier(0);

        // ---- swapped QK^T: sacc[t] = S^T (keys 32t.. x 32 q), log2 units ----
        f32x16 sacc[2];
        #pragma unroll
        for (int t = 0; t < 2; ++t)
            #pragma unroll
            for (int j = 0; j < 16; ++j) sacc[t][j] = 0.0f;
        __builtin_amdgcn_s_setprio(1);
        #pragma unroll
        for (int t = 0; t < 2; ++t) {
            const int row = 32 * t + l31;
            const char* krow = (const char*)k_lds + row * 256;
            const int sw = (row & 7) << 4;
            #pragma unroll
            for (int kss = 0; kss < 8; ++kss) {
                bf16x8 af = *(const bf16x8*)(krow + ((32 * kss + 16 * hi2) ^ sw));
                sacc[t] = __builtin_amdgcn_mfma_f32_32x32x16_bf16(af, qf[kss], sacc[t], 0, 0, 0);
            }
        }
        __builtin_amdgcn_s_setprio(0);

        // ---- softmax: p = exp2(s'), mask via bit tile, f32 row-sum, pack bf16 ----
        const u32x2 mq = *(const u32x2*)(&m_lds[(32 * wv + l31) * 2]);
        uint32_t pw[2][8];
        #pragma unroll
        for (int t = 0; t < 2; ++t) {
            #pragma unroll
            for (int rr = 0; rr < 4; ++rr) {
                const uint32_t mn = ((t ? mq.y : mq.x) >> (8 * rr + 4 * hi2)) & 0xFu;
                float em[4];
                #pragma unroll
                for (int c = 0; c < 4; ++c) {
                    const float e = EXP2(sacc[t][4 * rr + c]);
                    em[c] = ((mn >> c) & 1u) ? 0.0f : e;
                }
                psum += (em[0] + em[1]) + (em[2] + em[3]);
                pw[t][2 * rr]     = cvtpk(em[0], em[1]);
                pw[t][2 * rr + 1] = cvtpk(em[2], em[3]);
            }
        }

        // ---- PV: O[32q x 128d] += P[32x64] * V[64x128] ----
        #pragma unroll
        for (int t = 0; t < 2; ++t) {
            #pragma unroll
            for (int kss = 0; kss < 2; ++kss) {
                uint32_t a0 = pw[t][4 * kss + 0], b0 = pw[t][4 * kss + 2];
                uint32_t a1 = pw[t][4 * kss + 1], b1 = pw[t][4 * kss + 3];
                perm32swap(a0, b0);
                perm32swap(a1, b1);
                FragU af;
                af.u[0] = a0; af.u[1] = a1; af.u[2] = b0; af.u[3] = b1;
                const int keyb = 64 * t + 32 * kss + 16 * hi2;
                __builtin_amdgcn_s_setprio(1);
                #pragma unroll
                for (int dt = 0; dt < 4; ++dt) {
                    const int drow = 32 * dt + l31;
                    const char* vrow = (const char*)vt_lds + drow * 128;
                    const int sw8 = (drow & 15) << 3;
                    FragU vf;
                    *(u32x2*)&vf.u[0] = *(const u32x2*)(vrow + ((keyb)     ^ sw8));
                    *(u32x2*)&vf.u[2] = *(const u32x2*)(vrow + ((keyb + 8) ^ sw8));
                    oacc[dt] = __builtin_amdgcn_mfma_f32_32x32x16_bf16(af.v, vf.v, oacc[dt], 0, 0, 0);
                }
                __builtin_amdgcn_s_setprio(0);
            }
        }
        __syncthreads();
    }

    // ---- epilogue ----
    psum += __shfl_xor(psum, 32);  // lane L: full key-range sum for q = L&31
    if constexpr (NSPLIT == 1) {
        float* obase = op + ((size_t)b * SLQ + (size_t)(q0 + 32 * wv)) * DD + l31;
        #pragma unroll
        for (int r = 0; r < 16; ++r) {
            const int qrow = (r & 3) + 8 * (r >> 2) + 4 * hi2;
            const float s  = __shfl(psum, qrow);
            const float rs = 1.0f / s;
            #pragma unroll
            for (int dt = 0; dt < 4; ++dt)
                obase[(size_t)qrow * DD + 32 * dt] = oacc[dt][r] * rs;
        }
    } else {
        // un-normalized num -> ws[ks], den -> ws[2*NUM + ks]
        float* nbase = wsp + (size_t)ks * NB * SLQ * DD +
                       ((size_t)b * SLQ + (size_t)(q0 + 32 * wv)) * DD + l31;
        #pragma unroll
        for (int r = 0; r < 16; ++r) {
            const int qrow = (r & 3) + 8 * (r >> 2) + 4 * hi2;
            #pragma unroll
            for (int dt = 0; dt < 4; ++dt)
                nbase[(size_t)qrow * DD + 32 * dt] = oacc[dt][r];
        }
        if (lane < 32) {
            float* den = wsp + (size_t)2 * NB * SLQ * DD + (size_t)ks * NB * SLQ;
            den[(size_t)b * SLQ + q0 + 32 * wv + l31] = psum;
        }
    }
}

// out = (num0+num1) / (den0+den1), fully memory-bound
__global__ __launch_bounds__(256, 8)
void combine2(const float* __restrict__ wsp, float* __restrict__ op)
{
    constexpr size_t NUM  = (size_t)NB * SLQ * DD;
    constexpr size_t NQ4  = NUM / 4;
    const float* den0 = wsp + 2 * NUM;
    const float* den1 = den0 + (size_t)NB * SLQ;
    const size_t stride = (size_t)gridDim.x * blockDim.x;
    for (size_t i = (size_t)blockIdx.x * blockDim.x + threadIdx.x; i < NQ4; i += stride) {
        const size_t q = i >> 5;  // DD/4 = 32 groups per q-row
        f32x4v n0 = ((const f32x4v*)wsp)[i];
        f32x4v n1 = ((const f32x4v*)(wsp + NUM))[i];
        const float rs = 1.0f / (den0[q] + den1[q]);
        f32x4v o;
        o.x = (n0.x + n1.x) * rs;
        o.y = (n0.y + n1.y) * rs;
        o.z = (n0.z + n1.z) * rs;
        o.w = (n0.w + n1.w) * rs;
        ((f32x4v*)op)[i] = o;
    }
}

extern "C" void kernel_launch(void* const* d_in, const int* in_sizes, int n_in,
                              void* d_out, int out_size, void* d_ws, size_t ws_size,
                              hipStream_t stream)
{
    const float* q = (const float*)d_in[0];
    const float* k = (const float*)d_in[1];
    const float* v = (const float*)d_in[2];
    const void*  m = d_in[3];
    float*       o = (float*)d_out;
    float*       w = (float*)d_ws;

    const size_t need = ((size_t)2 * NB * SLQ * DD + (size_t)2 * NB * SLQ) * sizeof(float);
    if (ws_size >= need) {
        hipLaunchKernelGGL((attn_fwd<2>), dim3(1024), dim3(256), 0, stream, q, k, v, m, o, w);
        hipLaunchKernelGGL(combine2, dim3(2048), dim3(256), 0, stream, w, o);
    } else {
        hipLaunchKernelGGL((attn_fwd<1>), dim3(512), dim3(256), 0, stream, q, k, v, m, o, w);
    }
}

// Round 9
// 215.525 us; speedup vs baseline: 4.3491x; 4.3491x over previous
//
#include <hip/hip_runtime.h>
#include <stdint.h>

// Problem constants (B, LQ, LK, D fixed by the reference)
#define NB    32
#define SLQ   2048
#define SLK   2048
#define DD    128
#define QTILE 256          // q rows per workgroup (8 waves x 32)
#define KVB   64           // keys per block iteration
#define NKB   (SLK / KVB)  // 32

typedef __attribute__((ext_vector_type(8)))  short    bf16x8;
typedef __attribute__((ext_vector_type(16))) float    f32x16;
typedef __attribute__((ext_vector_type(4)))  float    f32x4v;
typedef __attribute__((ext_vector_type(4)))  uint32_t u32x4;
typedef __attribute__((ext_vector_type(2)))  uint32_t u32x2;

union FragU { uint32_t u[4]; bf16x8 v; };

// HW packed f32->bf16 (RNE), 1 inst per pair
__device__ __forceinline__ uint32_t cvtpk(float lo, float hi) {
    uint32_t r;
    asm("v_cvt_pk_bf16_f32 %0, %1, %2" : "=v"(r) : "v"(lo), "v"(hi));
    return r;
}
// a' = {lanes<32: a, lanes>=32: b[lane-32]}; b' = {lanes<32: a[lane+32], lanes>=32: b}
__device__ __forceinline__ void perm32swap(uint32_t& a, uint32_t& b) {
    asm("v_permlane32_swap_b32 %0, %1" : "+v"(a), "+v"(b));
}
// 16 mask bytes (0/1) -> 16 bits
__device__ __forceinline__ uint32_t pack16(u32x4 a) {
    uint32_t r0 = (((a.x & 0x01010101u) * 0x01020408u) >> 24) & 0xFu;
    uint32_t r1 = (((a.y & 0x01010101u) * 0x01020408u) >> 24) & 0xFu;
    uint32_t r2 = (((a.z & 0x01010101u) * 0x01020408u) >> 24) & 0xFu;
    uint32_t r3 = (((a.w & 0x01010101u) * 0x01020408u) >> 24) & 0xFu;
    return r0 | (r1 << 4) | (r2 << 8) | (r3 << 12);
}
#if __has_builtin(__builtin_amdgcn_exp2f)
#define EXP2(x) __builtin_amdgcn_exp2f(x)
#else
#define EXP2(x) exp2f(x)
#endif

// LDS-only barrier: lgkmcnt(0) + s_barrier, NO vmcnt drain (in-flight global
// prefetch loads cross it). sched_barrier fences per guide rule #18.
__device__ __forceinline__ void barrier_lgkm() {
    __builtin_amdgcn_sched_barrier(0);
    asm volatile("s_waitcnt lgkmcnt(0)\n\ts_barrier" ::: "memory");
    __builtin_amdgcn_sched_barrier(0);
}

__global__ __launch_bounds__(512, 2)
void attn_fwd(const float* __restrict__ qp, const float* __restrict__ kp,
              const float* __restrict__ vp, const void* __restrict__ mp,
              float* __restrict__ op)
{
    // Single-buffer LDS: 16KB K + 16KB V^T + 2KB mask bits = 34KB
    __shared__ short    k_lds[KVB * DD];    // [64 key][128 d] bf16, 16B-XOR swizzle
    __shared__ short    vt_lds[DD * KVB];   // [128 d][64 key] bf16, 8B-XOR swizzle
    __shared__ uint32_t m_lds[QTILE * 2];   // [256 q][2] dwords of key-bits
    __shared__ int      det_flags;

    const int tid  = threadIdx.x;
    const int lane = tid & 63;
    const int wv   = tid >> 6;   // wave 0..7, owns q rows [q0+32*wv, +32)
    const int l31  = lane & 31;
    const int hi2  = lane >> 5;  // 0/1

    // XCD-chunked swizzle: 256 WGs, 8 XCDs -> 32 consecutive work ids each
    const int bid = blockIdx.x;
    const int wg  = (bid & 7) * 32 + (bid >> 3);
    const int b   = wg >> 3;            // batch
    const int q0  = (wg & 7) * QTILE;   // q tile origin

    // ---- mask dtype self-detection (R2 FETCH proved u8; keep as safety) ----
    if (tid == 0) det_flags = 0;
    __syncthreads();
    {
        const u32x4 w = *(const u32x4*)((const char*)mp + tid * 16);
        const uint32_t any_hi    = (w.x | w.y | w.z | w.w) & 0xFFFFFF00u;
        const uint32_t any_mod84 = (w.y | w.w) & 0xFFu;
        const int f = (any_hi ? 1 : 0) | (any_mod84 ? 2 : 0);
        if (f) atomicOr(&det_flags, f);
    }
    __syncthreads();
    const int mflags = det_flags;
    const int mmode  = (mflags & 1) ? 0 : ((mflags & 2) ? 1 : 2);  // 0=u8, 1=i32, 2=i64

    // scale = log2(e)/sqrt(128): scores land in log2 units -> softmax is bare v_exp
    const float qsc = 0.12751744846458246f;

    // ---- persistent Q fragments (B-operand of swapped QK^T) ----
    bf16x8 qf[8];
    {
        const float* qrow = qp + ((size_t)b * SLQ + (size_t)(q0 + wv * 32 + l31)) * DD;
        #pragma unroll
        for (int ks = 0; ks < 8; ++ks) {
            f32x4v x0 = *(const f32x4v*)(qrow + 16 * ks + 8 * hi2);
            f32x4v x1 = *(const f32x4v*)(qrow + 16 * ks + 8 * hi2 + 4);
            FragU f;
            f.u[0] = cvtpk(x0.x * qsc, x0.y * qsc);
            f.u[1] = cvtpk(x0.z * qsc, x0.w * qsc);
            f.u[2] = cvtpk(x1.x * qsc, x1.y * qsc);
            f.u[3] = cvtpk(x1.z * qsc, x1.w * qsc);
            qf[ks] = f.v;
        }
    }

    f32x16 oacc[4];
    #pragma unroll
    for (int i = 0; i < 4; ++i)
        #pragma unroll
        for (int j = 0; j < 16; ++j) oacc[i][j] = 0.0f;
    float psum = 0.0f;

    const float* kb0 = kp + (size_t)b * SLK * DD;
    const float* vb0 = vp + (size_t)b * SLK * DD;
    const size_t mrow0 = ((size_t)b * SLQ + q0) * SLK;

    // ---- prefetch registers (T14), split across 512 threads ----
    f32x4v kreg[4];
    float  vreg[16];
    u32x4  mreg[2];

    const int vd  = tid & 127;       // d-row this thread stages for V^T
    const int vg  = tid >> 7;        // 0..3 -> keys 16*vg .. +15
    const int mqq = tid >> 1;        // mask q row (0..255)
    const int mh  = tid & 1;         // mask key half
    const int swv = (vd & 15) << 3;  // V^T 8B-granular XOR

    #define LOAD_TILE(KB)                                                         \
        do {                                                                      \
            const int k0_ = (KB) * KVB;                                           \
            const float* kbase_ = kb0 + (size_t)k0_ * DD;                         \
            _Pragma("unroll")                                                     \
            for (int j = 0; j < 4; ++j)                                           \
                kreg[j] = *(const f32x4v*)(kbase_ + (j * 512 + tid) * 4);         \
            const float* vcol_ = vb0 + ((size_t)k0_ + 16 * vg) * DD + vd;         \
            _Pragma("unroll")                                                     \
            for (int jj = 0; jj < 16; ++jj) vreg[jj] = vcol_[(size_t)jj * DD];    \
            if (mmode == 0) {                                                     \
                const uint8_t* ms_ = (const uint8_t*)mp + mrow0 +                 \
                                     (size_t)mqq * SLK + k0_ + mh * 32;           \
                mreg[0] = *(const u32x4*)(ms_);                                   \
                mreg[1] = *(const u32x4*)(ms_ + 16);                              \
            }                                                                     \
        } while (0)

    #define WRITE_LDS(KB)                                                         \
        do {                                                                      \
            _Pragma("unroll")                                                     \
            for (int j = 0; j < 4; ++j) {                                         \
                const int flat = (j * 512 + tid) * 4;                             \
                const int kk   = flat >> 7;                                       \
                const int dd2  = (flat & 127) * 2;                                \
                u32x2 w2;                                                         \
                w2.x = cvtpk(kreg[j].x, kreg[j].y);                               \
                w2.y = cvtpk(kreg[j].z, kreg[j].w);                               \
                *(u32x2*)((char*)k_lds + kk * 256 + (dd2 ^ ((kk & 15) << 4))) = w2;\
            }                                                                     \
            {                                                                     \
                char* vrow_ = (char*)vt_lds + vd * 128;                           \
                _Pragma("unroll")                                                 \
                for (int j = 0; j < 4; ++j) {                                     \
                    u32x2 w2;                                                     \
                    w2.x = cvtpk(vreg[4 * j + 0], vreg[4 * j + 1]);               \
                    w2.y = cvtpk(vreg[4 * j + 2], vreg[4 * j + 3]);               \
                    *(u32x2*)(vrow_ + ((32 * vg + 8 * j) ^ swv)) = w2;            \
                }                                                                 \
            }                                                                     \
            if (mmode == 0) {                                                     \
                m_lds[mqq * 2 + mh] = pack16(mreg[0]) | (pack16(mreg[1]) << 16);  \
            } else {                                                              \
                const size_t e0_ = mrow0 + (size_t)mqq * SLK + (KB) * KVB + mh * 32; \
                uint32_t bits = 0;                                                \
                if (mmode == 1) {                                                 \
                    const uint32_t* s_ = (const uint32_t*)mp + e0_;               \
                    for (int j = 0; j < 32; ++j) bits |= (s_[j] ? 1u : 0u) << j;  \
                } else {                                                          \
                    const uint64_t* s_ = (const uint64_t*)mp + e0_;               \
                    for (int j = 0; j < 32; ++j) bits |= (s_[j] ? 1u : 0u) << j;  \
                }                                                                 \
                m_lds[mqq * 2 + mh] = bits;                                       \
            }                                                                     \
        } while (0)

    LOAD_TILE(0);

    for (int kb = 0; kb < NKB; ++kb) {
        // ---- write LDS from prefetch regs; compiler's incremental vmcnt
        //      waits land here, after a full compute phase hid the loads ----
        WRITE_LDS(kb);
        barrier_lgkm();

        // ---- issue next tile's loads, pinned above compute; they stay in
        //      flight across the end-of-iter barrier (no vmcnt drain) ----
        if (kb + 1 < NKB) LOAD_TILE(kb + 1);
        __builtin_amdgcn_sched_barrier(0);

        // ---- swapped QK^T: sacc[t] = S^T (keys 32t.. x 32 q), log2 units ----
        f32x16 sacc[2];
        #pragma unroll
        for (int t = 0; t < 2; ++t)
            #pragma unroll
            for (int j = 0; j < 16; ++j) sacc[t][j] = 0.0f;
        __builtin_amdgcn_s_setprio(1);
        #pragma unroll
        for (int t = 0; t < 2; ++t) {
            const int row = 32 * t + l31;
            const char* krow = (const char*)k_lds + row * 256;
            const int sw = (row & 15) << 4;
            #pragma unroll
            for (int ks = 0; ks < 8; ++ks) {
                bf16x8 af = *(const bf16x8*)(krow + ((32 * ks + 16 * hi2) ^ sw));
                sacc[t] = __builtin_amdgcn_mfma_f32_32x32x16_bf16(af, qf[ks], sacc[t], 0, 0, 0);
            }
        }
        __builtin_amdgcn_s_setprio(0);

        // ---- softmax: p = exp2(s'), mask via bit tile, f32 row-sum, pack bf16 ----
        const u32x2 mq = *(const u32x2*)(&m_lds[(32 * wv + l31) * 2]);
        uint32_t pw[2][8];
        #pragma unroll
        for (int t = 0; t < 2; ++t) {
            #pragma unroll
            for (int rr = 0; rr < 4; ++rr) {
                const uint32_t mn = ((t ? mq.y : mq.x) >> (8 * rr + 4 * hi2)) & 0xFu;
                float em[4];
                #pragma unroll
                for (int c = 0; c < 4; ++c) {
                    const float e = EXP2(sacc[t][4 * rr + c]);
                    em[c] = ((mn >> c) & 1u) ? 0.0f : e;
                }
                psum += (em[0] + em[1]) + (em[2] + em[3]);
                pw[t][2 * rr]     = cvtpk(em[0], em[1]);
                pw[t][2 * rr + 1] = cvtpk(em[2], em[3]);
            }
        }

        // ---- PV: O[32q x 128d] += P[32x64] * V[64x128] ----
        #pragma unroll
        for (int t = 0; t < 2; ++t) {
            #pragma unroll
            for (int kss = 0; kss < 2; ++kss) {
                uint32_t a0 = pw[t][4 * kss + 0], b0 = pw[t][4 * kss + 2];
                uint32_t a1 = pw[t][4 * kss + 1], b1 = pw[t][4 * kss + 3];
                perm32swap(a0, b0);
                perm32swap(a1, b1);
                FragU af;
                af.u[0] = a0; af.u[1] = a1; af.u[2] = b0; af.u[3] = b1;
                const int keyb = 64 * t + 32 * kss + 16 * hi2;
                __builtin_amdgcn_s_setprio(1);
                #pragma unroll
                for (int dt = 0; dt < 4; ++dt) {
                    const int drow = 32 * dt + l31;
                    const char* vrow = (const char*)vt_lds + drow * 128;
                    const int sw8 = (drow & 15) << 3;
                    FragU vf;
                    *(u32x2*)&vf.u[0] = *(const u32x2*)(vrow + ((keyb)     ^ sw8));
                    *(u32x2*)&vf.u[2] = *(const u32x2*)(vrow + ((keyb + 8) ^ sw8));
                    oacc[dt] = __builtin_amdgcn_mfma_f32_32x32x16_bf16(af.v, vf.v, oacc[dt], 0, 0, 0);
                }
                __builtin_amdgcn_s_setprio(0);
            }
        }
        barrier_lgkm();  // LDS-only sync; prefetch loads remain in flight
    }

    // ---- epilogue: combine halves of row-sums, normalize, store fp32 ----
    psum += __shfl_xor(psum, 32);
    float* obase = op + ((size_t)b * SLQ + (size_t)(q0 + 32 * wv)) * DD + l31;
    #pragma unroll
    for (int r = 0; r < 16; ++r) {
        const int qrow = (r & 3) + 8 * (r >> 2) + 4 * hi2;
        const float s  = __shfl(psum, qrow);
        const float rs = 1.0f / s;
        #pragma unroll
        for (int dt = 0; dt < 4; ++dt) {
            obase[(size_t)qrow * DD + 32 * dt] = oacc[dt][r] * rs;
        }
    }
}

extern "C" void kernel_launch(void* const* d_in, const int* in_sizes, int n_in,
                              void* d_out, int out_size, void* d_ws, size_t ws_size,
                              hipStream_t stream)
{
    const float* q = (const float*)d_in[0];
    const float* k = (const float*)d_in[1];
    const float* v = (const float*)d_in[2];
    const void*  m = d_in[3];
    float*       o = (float*)d_out;
    hipLaunchKernelGGL(attn_fwd, dim3((NB * SLQ) / QTILE), dim3(512), 0, stream,
                       q, k, v, m, o);
}

// Round 10
// 205.157 us; speedup vs baseline: 4.5689x; 1.0505x over previous
//
#include <hip/hip_runtime.h>
#include <stdint.h>

// Problem constants (B, LQ, LK, D fixed by the reference)
#define NB    32
#define SLQ   2048
#define SLK   2048
#define DD    128
#define QTILE 128          // q rows per workgroup (8 waves x 16)
#define KVB   64           // keys per block iteration
#define NKB   (SLK / KVB)  // 32

typedef __attribute__((ext_vector_type(8)))  short    bf16x8;
typedef __attribute__((ext_vector_type(4)))  float    f32x4v;
typedef __attribute__((ext_vector_type(4)))  uint32_t u32x4;
typedef __attribute__((ext_vector_type(2)))  uint32_t u32x2;

union FragU { uint32_t u[4]; bf16x8 v; };

// HW packed f32->bf16 (RNE), 1 inst per pair
__device__ __forceinline__ uint32_t cvtpk(float lo, float hi) {
    uint32_t r;
    asm("v_cvt_pk_bf16_f32 %0, %1, %2" : "=v"(r) : "v"(lo), "v"(hi));
    return r;
}
// 16 mask bytes (0/1) -> 16 bits
__device__ __forceinline__ uint32_t pack16(u32x4 a) {
    uint32_t r0 = (((a.x & 0x01010101u) * 0x01020408u) >> 24) & 0xFu;
    uint32_t r1 = (((a.y & 0x01010101u) * 0x01020408u) >> 24) & 0xFu;
    uint32_t r2 = (((a.z & 0x01010101u) * 0x01020408u) >> 24) & 0xFu;
    uint32_t r3 = (((a.w & 0x01010101u) * 0x01020408u) >> 24) & 0xFu;
    return r0 | (r1 << 4) | (r2 << 8) | (r3 << 12);
}
#if __has_builtin(__builtin_amdgcn_exp2f)
#define EXP2(x) __builtin_amdgcn_exp2f(x)
#else
#define EXP2(x) exp2f(x)
#endif

__global__ __launch_bounds__(512, 4)   // cap 128 regs/thread total -> 4 waves/SIMD
void attn_fwd(const float* __restrict__ qp, const float* __restrict__ kp,
              const float* __restrict__ vp, const void* __restrict__ mp,
              float* __restrict__ op)
{
    // Single-buffer LDS (R5-proven 2-barrier schedule): 16K K + 16K V^T + 1K mask
    __shared__ short    k_lds[KVB * DD];    // [64 key][128 d] bf16, 16B-XOR swizzle
    __shared__ short    vt_lds[DD * KVB];   // [128 d][64 key] bf16, 8B-XOR swizzle
    __shared__ uint32_t m_lds[QTILE * 2];   // [128 q][2] dwords of key-bits
    __shared__ int      det_flags;

    const int tid  = threadIdx.x;
    const int lane = tid & 63;
    const int wv   = tid >> 6;    // wave 0..7, owns q rows [q0+16*wv, +16)
    const int m16  = lane & 15;   // q-col (QK^T) / d-col (PV)
    const int h4   = lane >> 4;   // k-slot group 0..3

    // XCD-chunked swizzle: 512 WGs, 8 XCDs -> 64 consecutive work ids each
    const int bid = blockIdx.x;
    const int wg  = (bid & 7) * 64 + (bid >> 3);
    const int b   = wg >> 4;            // batch
    const int q0  = (wg & 15) * QTILE;  // q tile origin

    // ---- mask dtype self-detection (R2 FETCH proved u8; keep as safety) ----
    if (tid == 0) det_flags = 0;
    __syncthreads();
    if (tid < 256) {
        const u32x4 w = *(const u32x4*)((const char*)mp + tid * 16);
        const uint32_t any_hi    = (w.x | w.y | w.z | w.w) & 0xFFFFFF00u;
        const uint32_t any_mod84 = (w.y | w.w) & 0xFFu;
        const int f = (any_hi ? 1 : 0) | (any_mod84 ? 2 : 0);
        if (f) atomicOr(&det_flags, f);
    }
    __syncthreads();
    const int mflags = det_flags;
    const int mmode  = (mflags & 1) ? 0 : ((mflags & 2) ? 1 : 2);  // 0=u8, 1=i32, 2=i64

    // scale = log2(e)/sqrt(128): scores in log2 units -> softmax is bare v_exp
    const float qsc = 0.12751744846458246f;

    // ---- persistent Q fragments: B-operand of swapped QK^T ----
    // B col = q = m16; slot (h4, j) holds Q[q][32*ks + 8*h4 + j]  (A==B k-map)
    bf16x8 qf[4];
    {
        const float* qrow = qp + ((size_t)b * SLQ + (size_t)(q0 + 16 * wv + m16)) * DD;
        #pragma unroll
        for (int ks = 0; ks < 4; ++ks) {
            f32x4v x0 = *(const f32x4v*)(qrow + 32 * ks + 8 * h4);
            f32x4v x1 = *(const f32x4v*)(qrow + 32 * ks + 8 * h4 + 4);
            FragU f;
            f.u[0] = cvtpk(x0.x * qsc, x0.y * qsc);
            f.u[1] = cvtpk(x0.z * qsc, x0.w * qsc);
            f.u[2] = cvtpk(x1.x * qsc, x1.y * qsc);
            f.u[3] = cvtpk(x1.z * qsc, x1.w * qsc);
            qf[ks] = f.v;
        }
    }

    // per-wave output: O[16q x 128d] as 8 d-tiles of 16: lane holds
    // O[q = 4*h4 + r][d = 16*dt + m16]  (16x16 C-map, m89-verified)
    f32x4v oacc[8];
    #pragma unroll
    for (int i = 0; i < 8; ++i)
        #pragma unroll
        for (int j = 0; j < 4; ++j) oacc[i][j] = 0.0f;
    float psum = 0.0f;  // exp-sum over this lane's key slots for q = m16

    const float* kb0 = kp + (size_t)b * SLK * DD;
    const float* vb0 = vp + (size_t)b * SLK * DD;
    const size_t mrow0 = ((size_t)b * SLQ + q0) * SLK;

    // ---- prefetch registers (T14), split across 512 threads ----
    f32x4v kreg[4];
    float  vreg[16];
    u32x4  mreg;

    const int vd  = tid & 127;       // d-row this thread stages for V^T
    const int vg  = tid >> 7;        // 0..3 -> keys 16*vg .. +15
    const int mqq = tid >> 2;        // mask q row (0..127)
    const int mpt = tid & 3;         // mask 16-key part
    const int swv = (vd & 15) << 3;  // V^T 8B-granular XOR

    #define LOAD_TILE(KB)                                                         \
        do {                                                                      \
            const int k0_ = (KB) * KVB;                                           \
            const float* kbase_ = kb0 + (size_t)k0_ * DD;                         \
            _Pragma("unroll")                                                     \
            for (int j = 0; j < 4; ++j)                                           \
                kreg[j] = *(const f32x4v*)(kbase_ + (j * 512 + tid) * 4);         \
            const float* vcol_ = vb0 + ((size_t)k0_ + 16 * vg) * DD + vd;         \
            _Pragma("unroll")                                                     \
            for (int jj = 0; jj < 16; ++jj) vreg[jj] = vcol_[(size_t)jj * DD];    \
            if (mmode == 0) {                                                     \
                mreg = *(const u32x4*)((const uint8_t*)mp + mrow0 +               \
                                       (size_t)mqq * SLK + k0_ + 16 * mpt);       \
            }                                                                     \
        } while (0)

    #define WRITE_LDS(KB)                                                         \
        do {                                                                      \
            _Pragma("unroll")                                                     \
            for (int j = 0; j < 4; ++j) {                                         \
                const int fc  = j * 512 + tid;   /* 16B-chunk id in 64x128 f32 */ \
                const int kk  = fc >> 5;                                          \
                const int db  = (fc & 31) * 8;   /* byte offset in bf16 row */    \
                u32x2 w2;                                                         \
                w2.x = cvtpk(kreg[j].x, kreg[j].y);                               \
                w2.y = cvtpk(kreg[j].z, kreg[j].w);                               \
                *(u32x2*)((char*)k_lds + kk * 256 + (db ^ ((kk & 15) << 4))) = w2;\
            }                                                                     \
            {                                                                     \
                char* vrow_ = (char*)vt_lds + vd * 128;                           \
                _Pragma("unroll")                                                 \
                for (int j = 0; j < 4; ++j) {                                     \
                    u32x2 w2;                                                     \
                    w2.x = cvtpk(vreg[4 * j + 0], vreg[4 * j + 1]);               \
                    w2.y = cvtpk(vreg[4 * j + 2], vreg[4 * j + 3]);               \
                    *(u32x2*)(vrow_ + ((32 * vg + 8 * j) ^ swv)) = w2;            \
                }                                                                 \
            }                                                                     \
            if (mmode == 0) {                                                     \
                ((uint16_t*)m_lds)[mqq * 4 + mpt] = (uint16_t)pack16(mreg);       \
            } else {                                                              \
                const size_t e0_ = mrow0 + (size_t)mqq * SLK + (KB) * KVB + 16 * mpt; \
                uint32_t bits = 0;                                                \
                if (mmode == 1) {                                                 \
                    const uint32_t* s_ = (const uint32_t*)mp + e0_;               \
                    for (int j = 0; j < 16; ++j) bits |= (s_[j] ? 1u : 0u) << j;  \
                } else {                                                          \
                    const uint64_t* s_ = (const uint64_t*)mp + e0_;               \
                    for (int j = 0; j < 16; ++j) bits |= (s_[j] ? 1u : 0u) << j;  \
                }                                                                 \
                ((uint16_t*)m_lds)[mqq * 4 + mpt] = (uint16_t)bits;               \
            }                                                                     \
        } while (0)

    LOAD_TILE(0);

    for (int kb = 0; kb < NKB; ++kb) {
        // ---- write LDS from prefetch regs (vmcnt waits land here, covered) ----
        WRITE_LDS(kb);
        __syncthreads();

        // ---- issue next tile's loads, pinned above compute ----
        if (kb + 1 < NKB) LOAD_TILE(kb + 1);
        __builtin_amdgcn_sched_barrier(0);

        // mask bits for this lane's q-row (q = 16wv + m16)
        const u32x2 mq = *(const u32x2*)(&m_lds[(16 * wv + m16) * 2]);

        uint32_t pw[2][2];  // P bf16 pairs for the live kg-pair
        #pragma unroll
        for (int pair = 0; pair < 2; ++pair) {
            // ---- two 16-key groups: swapped QK^T -> softmax -> pack ----
            #pragma unroll
            for (int sub = 0; sub < 2; ++sub) {
                const int kg = 2 * pair + sub;       // key group 0..3
                const int krow = 16 * kg + m16;      // A row = key
                const char* kr = (const char*)k_lds + krow * 256;
                const int sw = (krow & 15) << 4;
                f32x4v sacc = {0.0f, 0.0f, 0.0f, 0.0f};
                __builtin_amdgcn_s_setprio(1);
                #pragma unroll
                for (int ks = 0; ks < 4; ++ks) {
                    // A slot (h4,j) = K[krow][32ks + 8h4 + j]  (A==B k-map)
                    bf16x8 af = *(const bf16x8*)(kr + ((64 * ks + 16 * h4) ^ sw));
                    sacc = __builtin_amdgcn_mfma_f32_16x16x32_bf16(af, qf[ks], sacc, 0, 0, 0);
                }
                __builtin_amdgcn_s_setprio(0);
                // C: col = q = m16, row(key rel) = 4*h4 + r  [m89-verified]
                const uint32_t mword = (kg & 2) ? mq.y : mq.x;
                const uint32_t mn = (mword >> ((kg & 1) * 16 + 4 * h4)) & 0xFu;
                float em[4];
                #pragma unroll
                for (int c = 0; c < 4; ++c) {
                    const float e = EXP2(sacc[c]);
                    em[c] = ((mn >> c) & 1u) ? 0.0f : e;
                }
                psum += (em[0] + em[1]) + (em[2] + em[3]);
                pw[sub][0] = cvtpk(em[0], em[1]);
                pw[sub][1] = cvtpk(em[2], em[3]);
            }

            // ---- PV over this 32-key pair: O[16q x 128d] += P * V ----
            // A slot (h4,j): j 0..3 -> key 32*pair + 4*h4 + j (from kg even),
            //                j 4..7 -> key 32*pair + 16 + 4*h4 + (j-4) (kg odd).
            // B reads V^T rows in the SAME slot order -> k-map cancels.
            FragU af;
            af.u[0] = pw[0][0]; af.u[1] = pw[0][1];
            af.u[2] = pw[1][0]; af.u[3] = pw[1][1];
            const int kbyte0 = (32 * pair + 4 * h4) * 2;
            __builtin_amdgcn_s_setprio(1);
            #pragma unroll
            for (int dt = 0; dt < 8; ++dt) {
                const int drow = 16 * dt + m16;
                const char* vrow = (const char*)vt_lds + drow * 128;
                const int sw8 = (drow & 15) << 3;
                FragU vf;
                *(u32x2*)&vf.u[0] = *(const u32x2*)(vrow + ((kbyte0)      ^ sw8));
                *(u32x2*)&vf.u[2] = *(const u32x2*)(vrow + ((kbyte0 + 32) ^ sw8));
                oacc[dt] = __builtin_amdgcn_mfma_f32_16x16x32_bf16(af.v, vf.v, oacc[dt], 0, 0, 0);
            }
            __builtin_amdgcn_s_setprio(0);
        }
        __syncthreads();
    }

    // ---- epilogue: reduce psum across the 4 h-groups, normalize, store ----
    psum += __shfl_xor(psum, 16);
    psum += __shfl_xor(psum, 32);   // all lanes: total for q-sub = m16
    float* obase = op + ((size_t)b * SLQ + (size_t)(q0 + 16 * wv)) * DD + m16;
    #pragma unroll
    for (int r = 0; r < 4; ++r) {
        const int qsub = 4 * h4 + r;
        const float rs = 1.0f / __shfl(psum, qsub);  // total for q-sub = qsub
        #pragma unroll
        for (int dt = 0; dt < 8; ++dt) {
            obase[(size_t)qsub * DD + 16 * dt] = oacc[dt][r] * rs;
        }
    }
}

extern "C" void kernel_launch(void* const* d_in, const int* in_sizes, int n_in,
                              void* d_out, int out_size, void* d_ws, size_t ws_size,
                              hipStream_t stream)
{
    const float* q = (const float*)d_in[0];
    const float* k = (const float*)d_in[1];
    const float* v = (const float*)d_in[2];
    const void*  m = d_in[3];
    float*       o = (float*)d_out;
    hipLaunchKernelGGL(attn_fwd, dim3((NB * SLQ) / QTILE), dim3(512), 0, stream,
                       q, k, v, m, o);
}